// Round 1
// baseline (3403.394 us; speedup 1.0000x reference)
//
#include <hip/hip_runtime.h>
#include <hip/hip_bf16.h>

// ChebNet: N=100000 nodes, E=1600000 edges, IN=HID=128, OUT=40, K=3, 5 hidden layers.
// Layout decisions:
//  - CSR by dst built per-launch (ws is re-poisoned every call).
//  - dinv[i] = 1/sqrt(max(deg_i,1)) derived from row_ptr diffs.
//  - Per layer: B1 = -spmm(X); B2 = -2*spmm(B1) - X; H = relu([X|B1|B2] @ W + b)
//    where the GEMM reads the three K=128 blocks from separate buffers (no concat).

#define NN 100000
#define EE 1600000
#define FF 128

// ---------------- CSR build ----------------

__global__ void hist_kernel(const int* __restrict__ dst, int* __restrict__ cnt, int e) {
    int i = blockIdx.x * blockDim.x + threadIdx.x;
    if (i < e) atomicAdd(&cnt[dst[i]], 1);
}

__global__ void scan_kernel(const int* __restrict__ cnt, int* __restrict__ row_ptr, int n) {
    __shared__ int sums[1024];
    int tid = threadIdx.x;
    int chunk = (n + 1023) >> 10;
    int s = tid * chunk;
    int e = s + chunk; if (e > n) e = n;
    int local = 0;
    for (int i = s; i < e; ++i) local += cnt[i];
    sums[tid] = local;
    __syncthreads();
    for (int off = 1; off < 1024; off <<= 1) {
        int v = (tid >= off) ? sums[tid - off] : 0;
        __syncthreads();
        sums[tid] += v;
        __syncthreads();
    }
    int run = (tid == 0) ? 0 : sums[tid - 1];
    for (int i = s; i < e; ++i) { row_ptr[i] = run; run += cnt[i]; }
    if (e == n) row_ptr[n] = run;   // multiple writers all write the total; benign
}

__global__ void dinv_kernel(const int* __restrict__ row_ptr, float* __restrict__ dinv, int n) {
    int i = blockIdx.x * blockDim.x + threadIdx.x;
    if (i >= n) return;
    int d = row_ptr[i + 1] - row_ptr[i];
    if (d < 1) d = 1;
    dinv[i] = 1.0f / sqrtf((float)d);
}

__global__ void scatter_kernel(const int* __restrict__ src, const int* __restrict__ dst,
                               const int* __restrict__ row_ptr, int* __restrict__ fill,
                               int* __restrict__ col_src, int e) {
    int i = blockIdx.x * blockDim.x + threadIdx.x;
    if (i >= e) return;
    int d = dst[i];
    int pos = row_ptr[d] + atomicAdd(&fill[d], 1);
    col_src[pos] = src[i];
}

// ---------------- SpMM: out[d] = alpha*dinv[d]*sum_e dinv[src]*Xin[src] + beta*Xo[d] ----------------
// One 32-lane slot per node; lane handles one float4 of the 128-float row.

__global__ __launch_bounds__(256) void spmm_kernel(
    float* __restrict__ out, const float* __restrict__ Xin, const float* __restrict__ Xo,
    const float* __restrict__ dinv, const int* __restrict__ rp, const int* __restrict__ cs,
    float alpha, float beta, int n)
{
    int slot = threadIdx.x >> 5;
    int lane = threadIdx.x & 31;
    int node = blockIdx.x * 8 + slot;
    if (node >= n) return;
    const float4* X4 = (const float4*)Xin;
    float4 acc = make_float4(0.f, 0.f, 0.f, 0.f);
    int s = rp[node], e = rp[node + 1];
    for (int i = s; i < e; ++i) {
        int src = cs[i];
        float w = dinv[src];
        float4 x = X4[src * 32 + lane];
        acc.x += w * x.x; acc.y += w * x.y; acc.z += w * x.z; acc.w += w * x.w;
    }
    float sc = alpha * dinv[node];
    float4 r;
    if (beta != 0.f) {
        float4 o = ((const float4*)Xo)[node * 32 + lane];
        r.x = sc * acc.x + beta * o.x;
        r.y = sc * acc.y + beta * o.y;
        r.z = sc * acc.z + beta * o.z;
        r.w = sc * acc.w + beta * o.w;
    } else {
        r.x = sc * acc.x; r.y = sc * acc.y; r.z = sc * acc.z; r.w = sc * acc.w;
    }
    ((float4*)out)[node * 32 + lane] = r;
}

// ---------------- GEMM: H = relu([X0|X1|X2] @ W + b), W is (384 x OUTC) row-major ----------------
// Block computes 64 rows x 128 cols. Thread: 4 rows x 8 cols.

template <int OUTC>
__global__ __launch_bounds__(256) void gemm_relu_kernel(
    float* __restrict__ out, const float* __restrict__ X0, const float* __restrict__ X1,
    const float* __restrict__ X2, const float* __restrict__ W, const float* __restrict__ b, int n)
{
    __shared__ float Xs[64][33];
    __shared__ float Ws[32][128];
    int tid = threadIdx.x;
    int tcol = tid & 15;          // cols tcol*8 .. +7
    int trow = tid >> 4;          // rows trow*4 .. +3
    int row0 = blockIdx.x * 64;
    int c0 = tcol * 8;
    int r0 = trow * 4;

    float acc[4][8];
#pragma unroll
    for (int r = 0; r < 4; ++r)
#pragma unroll
        for (int j = 0; j < 8; ++j) acc[r][j] = 0.f;

    const float* Xsrc[3] = { X0, X1, X2 };

    for (int s = 0; s < 3; ++s) {
        const float* Xp = Xsrc[s];
        for (int k0 = 0; k0 < 128; k0 += 32) {
            // load X tile: 64 rows x 32 cols
#pragma unroll
            for (int i = 0; i < 8; ++i) {
                int flat = i * 256 + tid;
                int r = flat >> 5, c = flat & 31;
                int gr = row0 + r;
                Xs[r][c] = (gr < n) ? Xp[(size_t)gr * 128 + k0 + c] : 0.f;
            }
            // load W tile: 32 rows x 128 cols (zero-pad cols >= OUTC)
#pragma unroll
            for (int i = 0; i < 16; ++i) {
                int flat = i * 256 + tid;
                int r = flat >> 7, c = flat & 127;
                int gk = s * 128 + k0 + r;
                Ws[r][c] = (c < OUTC) ? W[gk * OUTC + c] : 0.f;
            }
            __syncthreads();
#pragma unroll 8
            for (int kk = 0; kk < 32; ++kk) {
                float4 wa = *(const float4*)&Ws[kk][c0];
                float4 wb = *(const float4*)&Ws[kk][c0 + 4];
                float w[8] = { wa.x, wa.y, wa.z, wa.w, wb.x, wb.y, wb.z, wb.w };
#pragma unroll
                for (int r = 0; r < 4; ++r) {
                    float xv = Xs[r0 + r][kk];
#pragma unroll
                    for (int j = 0; j < 8; ++j) acc[r][j] += xv * w[j];
                }
            }
            __syncthreads();
        }
    }

    float bias[8];
#pragma unroll
    for (int j = 0; j < 8; ++j) {
        int c = c0 + j;
        bias[j] = (c < OUTC) ? b[c] : 0.f;
    }
#pragma unroll
    for (int r = 0; r < 4; ++r) {
        int gr = row0 + r0 + r;
        if (gr >= n) continue;
#pragma unroll
        for (int j = 0; j < 8; ++j) {
            int c = c0 + j;
            if (c < OUTC) {
                float v = acc[r][j] + bias[j];
                out[(size_t)gr * OUTC + c] = v > 0.f ? v : 0.f;
            }
        }
    }
}

// ---------------- launch ----------------

extern "C" void kernel_launch(void* const* d_in, const int* in_sizes, int n_in,
                              void* d_out, int out_size, void* d_ws, size_t ws_size,
                              hipStream_t stream) {
    const float* features = (const float*)d_in[0];
    const int*   src      = (const int*)d_in[1];
    const int*   dst      = (const int*)d_in[2];
    const float* W0       = (const float*)d_in[3];
    const float* b0       = (const float*)d_in[4];
    const float* Wh       = (const float*)d_in[5];
    const float* bh       = (const float*)d_in[6];
    const float* Wl       = (const float*)d_in[7];
    const float* bl       = (const float*)d_in[8];
    float* out = (float*)d_out;

    const int N = NN, E = EE;

    char* ws = (char*)d_ws;
    size_t off = 0;
    auto alloc = [&](size_t bytes) -> void* {
        void* p = ws + off;
        off += (bytes + 511) & ~(size_t)511;
        return p;
    };
    float* dinv   = (float*)alloc((size_t)N * 4);
    int*   rowptr = (int*)alloc((size_t)(N + 1) * 4);
    int*   fill   = (int*)alloc((size_t)N * 4);
    int*   colsrc = (int*)alloc((size_t)E * 4);
    float* B1     = (float*)alloc((size_t)N * FF * 4);
    float* B2     = (float*)alloc((size_t)N * FF * 4);
    float* XA     = (float*)alloc((size_t)N * FF * 4);
    float* XB     = (float*)alloc((size_t)N * FF * 4);

    // CSR build
    hipMemsetAsync(fill, 0, (size_t)N * 4, stream);
    hist_kernel<<<(E + 255) / 256, 256, 0, stream>>>(dst, fill, E);
    scan_kernel<<<1, 1024, 0, stream>>>(fill, rowptr, N);
    dinv_kernel<<<(N + 255) / 256, 256, 0, stream>>>(rowptr, dinv, N);
    hipMemsetAsync(fill, 0, (size_t)N * 4, stream);
    scatter_kernel<<<(E + 255) / 256, 256, 0, stream>>>(src, dst, rowptr, fill, colsrc, E);

    const float* cur = features;
    float* nxt = XA;
    int spmm_grid = (N + 7) / 8;
    int gemm_grid = (N + 63) / 64;

    for (int layer = 0; layer < 7; ++layer) {
        const float* W; const float* b; int outc;
        if (layer == 0)      { W = W0; b = b0; outc = 128; }
        else if (layer < 6)  { W = Wh + (size_t)(layer - 1) * 384 * 128; b = bh + (layer - 1) * 128; outc = 128; }
        else                 { W = Wl; b = bl; outc = 40; }

        spmm_kernel<<<spmm_grid, 256, 0, stream>>>(B1, cur, cur, dinv, rowptr, colsrc, -1.f, 0.f, N);
        spmm_kernel<<<spmm_grid, 256, 0, stream>>>(B2, B1, cur, dinv, rowptr, colsrc, -2.f, -1.f, N);

        float* dstbuf = (layer == 6) ? out : nxt;
        if (outc == 128)
            gemm_relu_kernel<128><<<gemm_grid, 256, 0, stream>>>(dstbuf, cur, B1, B2, W, b, N);
        else
            gemm_relu_kernel<40><<<gemm_grid, 256, 0, stream>>>(dstbuf, cur, B1, B2, W, b, N);

        if (layer < 6) {
            const float* newcur = nxt;
            nxt = (nxt == XA) ? XB : XA;
            cur = newcur;
        }
    }
}

// Round 3
// 3104.304 us; speedup vs baseline: 1.0963x; 1.0963x over previous
//
#include <hip/hip_runtime.h>
#include <hip/hip_bf16.h>

// ChebNet: N=100000, E=1600000, IN=HID=128, OUT=40, K=3, 5 hidden layers.
//  - CSR by dst built per-launch.
//  - Per layer: B1 = -spmm(X); B2 = -2*spmm(B1) - X; H = relu([X|B1|B2] @ W + b)
//  - GEMM uses bf16x3 split (hi/lo) MFMA: A*B ~= Ah*Bh + Ah*Bl + Al*Bh, fp32 acc.

#define NN 100000
#define EE 1600000
#define FF 128

typedef __attribute__((ext_vector_type(8))) short short8_t;
typedef __attribute__((ext_vector_type(4))) short short4_t;
typedef __attribute__((ext_vector_type(4))) float floatx4;

// ---------------- CSR build ----------------

__global__ void hist_kernel(const int* __restrict__ dst, int* __restrict__ cnt, int e) {
    int i = blockIdx.x * blockDim.x + threadIdx.x;
    if (i < e) atomicAdd(&cnt[dst[i]], 1);
}

__global__ void scan_kernel(const int* __restrict__ cnt, int* __restrict__ row_ptr, int n) {
    __shared__ int sums[1024];
    int tid = threadIdx.x;
    int chunk = (n + 1023) >> 10;
    int s = tid * chunk;
    int e = s + chunk; if (e > n) e = n;
    int local = 0;
    for (int i = s; i < e; ++i) local += cnt[i];
    sums[tid] = local;
    __syncthreads();
    for (int off = 1; off < 1024; off <<= 1) {
        int v = (tid >= off) ? sums[tid - off] : 0;
        __syncthreads();
        sums[tid] += v;
        __syncthreads();
    }
    int run = (tid == 0) ? 0 : sums[tid - 1];
    for (int i = s; i < e; ++i) { row_ptr[i] = run; run += cnt[i]; }
    if (e == n) row_ptr[n] = run;
}

__global__ void dinv_kernel(const int* __restrict__ row_ptr, float* __restrict__ dinv, int n) {
    int i = blockIdx.x * blockDim.x + threadIdx.x;
    if (i >= n) return;
    int d = row_ptr[i + 1] - row_ptr[i];
    if (d < 1) d = 1;
    dinv[i] = 1.0f / sqrtf((float)d);
}

__global__ void scatter_kernel(const int* __restrict__ src, const int* __restrict__ dst,
                               const int* __restrict__ row_ptr, int* __restrict__ fill,
                               int* __restrict__ col_src, int e) {
    int i = blockIdx.x * blockDim.x + threadIdx.x;
    if (i >= e) return;
    int d = dst[i];
    int pos = row_ptr[d] + atomicAdd(&fill[d], 1);
    col_src[pos] = src[i];
}

// ---------------- SpMM ----------------

__global__ __launch_bounds__(256) void spmm_kernel(
    float* __restrict__ out, const float* __restrict__ Xin, const float* __restrict__ Xo,
    const float* __restrict__ dinv, const int* __restrict__ rp, const int* __restrict__ cs,
    float alpha, float beta, int n)
{
    int slot = threadIdx.x >> 5;
    int lane = threadIdx.x & 31;
    int node = blockIdx.x * 8 + slot;
    if (node >= n) return;
    const float4* X4 = (const float4*)Xin;
    float4 acc = make_float4(0.f, 0.f, 0.f, 0.f);
    int s = rp[node], e = rp[node + 1];
    for (int i = s; i < e; ++i) {
        int src = cs[i];
        float w = dinv[src];
        float4 x = X4[src * 32 + lane];
        acc.x += w * x.x; acc.y += w * x.y; acc.z += w * x.z; acc.w += w * x.w;
    }
    float sc = alpha * dinv[node];
    float4 r;
    if (beta != 0.f) {
        float4 o = ((const float4*)Xo)[node * 32 + lane];
        r.x = sc * acc.x + beta * o.x;
        r.y = sc * acc.y + beta * o.y;
        r.z = sc * acc.z + beta * o.z;
        r.w = sc * acc.w + beta * o.w;
    } else {
        r.x = sc * acc.x; r.y = sc * acc.y; r.z = sc * acc.z; r.w = sc * acc.w;
    }
    ((float4*)out)[node * 32 + lane] = r;
}

// ---------------- bf16x3 MFMA GEMM: H = relu([X0|X1|X2] @ W + b) ----------------

__device__ inline void f2bf_hilo(float x, short* hi, short* lo) {
    union { float f; unsigned u; } a; a.f = x;
    unsigned uh = a.u + 0x7FFFu + ((a.u >> 16) & 1u);
    unsigned short h = (unsigned short)(uh >> 16);
    union { unsigned u; float f; } hf; hf.u = ((unsigned)h) << 16;
    float r = x - hf.f;
    union { float f; unsigned u; } b; b.f = r;
    unsigned ul = b.u + 0x7FFFu + ((b.u >> 16) & 1u);
    *hi = (short)h; *lo = (short)(ul >> 16);
}

typedef __attribute__((ext_vector_type(4))) float accfrag;

template <int OUTC, int NT>
__global__ __launch_bounds__(256) void gemm_mfma_kernel(
    float* __restrict__ out, const float* __restrict__ X0, const float* __restrict__ X1,
    const float* __restrict__ X2, const float* __restrict__ W, const float* __restrict__ bias,
    int n)
{
    __shared__ short Ahi[128 * 40];
    __shared__ short Alo[128 * 40];
    __shared__ short Whi[NT * 16 * 40];
    __shared__ short Wlo[NT * 16 * 40];

    int tid = threadIdx.x;
    int row0 = blockIdx.x * 128;
    int lane = tid & 63;
    int wave = tid >> 6;
    int m15 = lane & 15;
    int quad = lane >> 4;

    accfrag acc[2][NT];
#pragma unroll
    for (int mi = 0; mi < 2; ++mi)
#pragma unroll
        for (int nj = 0; nj < NT; ++nj) acc[mi][nj] = (accfrag){0.f, 0.f, 0.f, 0.f};

    // zero the padded W columns (staging never touches them)
    if (OUTC != NT * 16) {
        for (int i = tid; i < (NT * 16 - OUTC) * 40; i += 256) {
            Whi[OUTC * 40 + i] = 0;
            Wlo[OUTC * 40 + i] = 0;
        }
    }

    for (int ks = 0; ks < 12; ++ks) {
        const float* Xp = (ks < 4) ? X0 : (ks < 8) ? X1 : X2;
        int k0in = (ks & 3) * 32;
        int k0g = ks * 32;

        // stage A: 128 rows x 32 k (fp32 -> bf16 hi/lo)
#pragma unroll
        for (int i = 0; i < 4; ++i) {
            int q = i * 256 + tid;          // [0,1024)
            int r = q >> 3;
            int kq = (q & 7) * 4;
            int gr = row0 + r;
            floatx4 v = {0.f, 0.f, 0.f, 0.f};
            if (gr < n) v = *(const floatx4*)&Xp[(size_t)gr * 128 + k0in + kq];
            short h[4], l[4];
            f2bf_hilo(v.x, &h[0], &l[0]);
            f2bf_hilo(v.y, &h[1], &l[1]);
            f2bf_hilo(v.z, &h[2], &l[2]);
            f2bf_hilo(v.w, &h[3], &l[3]);
            short4_t hv = { h[0], h[1], h[2], h[3] };
            short4_t lv = { l[0], l[1], l[2], l[3] };
            *(short4_t*)&Ahi[r * 40 + kq] = hv;
            *(short4_t*)&Alo[r * 40 + kq] = lv;
        }

        // stage W tile (32 x OUTC), transposed into LDS as [n][k]
        if (OUTC == 128) {
#pragma unroll
            for (int i = 0; i < 4; ++i) {
                int q = i * 256 + tid;      // [0,1024): kr = q>>5, c4=(q&31)*4
                int kr = q >> 5;
                int c4 = (q & 31) * 4;
                floatx4 v = *(const floatx4*)&W[(size_t)(k0g + kr) * 128 + c4];
                short h[4], l[4];
                f2bf_hilo(v.x, &h[0], &l[0]);
                f2bf_hilo(v.y, &h[1], &l[1]);
                f2bf_hilo(v.z, &h[2], &l[2]);
                f2bf_hilo(v.w, &h[3], &l[3]);
#pragma unroll
                for (int j = 0; j < 4; ++j) {
                    Whi[(c4 + j) * 40 + kr] = h[j];
                    Wlo[(c4 + j) * 40 + kr] = l[j];
                }
            }
        } else {
            // OUTC==40: 32 rows x 10 float4 = 320 float4s
#pragma unroll
            for (int i = 0; i < 2; ++i) {
                int q = i * 256 + tid;
                if (q < 320) {
                    int kr = q / 10;
                    int c4 = (q % 10) * 4;
                    floatx4 v = *(const floatx4*)&W[(size_t)(k0g + kr) * 40 + c4];
                    short h[4], l[4];
                    f2bf_hilo(v.x, &h[0], &l[0]);
                    f2bf_hilo(v.y, &h[1], &l[1]);
                    f2bf_hilo(v.z, &h[2], &l[2]);
                    f2bf_hilo(v.w, &h[3], &l[3]);
#pragma unroll
                    for (int j = 0; j < 4; ++j) {
                        Whi[(c4 + j) * 40 + kr] = h[j];
                        Wlo[(c4 + j) * 40 + kr] = l[j];
                    }
                }
            }
        }
        __syncthreads();

        // compute
        int mbase = wave * 32;
        short8_t a_hi[2], a_lo[2];
#pragma unroll
        for (int mi = 0; mi < 2; ++mi) {
            int off = (mbase + mi * 16 + m15) * 40 + quad * 8;
            a_hi[mi] = *(const short8_t*)&Ahi[off];
            a_lo[mi] = *(const short8_t*)&Alo[off];
        }
#pragma unroll
        for (int nj = 0; nj < NT; ++nj) {
            int off = (nj * 16 + m15) * 40 + quad * 8;
            short8_t b_hi = *(const short8_t*)&Whi[off];
            short8_t b_lo = *(const short8_t*)&Wlo[off];
#pragma unroll
            for (int mi = 0; mi < 2; ++mi) {
                acc[mi][nj] = __builtin_amdgcn_mfma_f32_16x16x32_bf16(a_hi[mi], b_hi, acc[mi][nj], 0, 0, 0);
                acc[mi][nj] = __builtin_amdgcn_mfma_f32_16x16x32_bf16(a_lo[mi], b_hi, acc[mi][nj], 0, 0, 0);
                acc[mi][nj] = __builtin_amdgcn_mfma_f32_16x16x32_bf16(a_hi[mi], b_lo, acc[mi][nj], 0, 0, 0);
            }
        }
        __syncthreads();
    }

    // epilogue: bias + relu + store. C/D: col=lane&15, row=quad*4+reg.
#pragma unroll
    for (int nj = 0; nj < NT; ++nj) {
        int col = nj * 16 + m15;
        float bv = (col < OUTC) ? bias[col] : 0.f;
#pragma unroll
        for (int mi = 0; mi < 2; ++mi) {
#pragma unroll
            for (int reg = 0; reg < 4; ++reg) {
                int gr = row0 + wave * 32 + mi * 16 + quad * 4 + reg;
                if (gr < n && col < OUTC) {
                    float v = acc[mi][nj][reg] + bv;
                    out[(size_t)gr * OUTC + col] = v > 0.f ? v : 0.f;
                }
            }
        }
    }
}

// ---------------- launch ----------------

extern "C" void kernel_launch(void* const* d_in, const int* in_sizes, int n_in,
                              void* d_out, int out_size, void* d_ws, size_t ws_size,
                              hipStream_t stream) {
    const float* features = (const float*)d_in[0];
    const int*   src      = (const int*)d_in[1];
    const int*   dst      = (const int*)d_in[2];
    const float* W0       = (const float*)d_in[3];
    const float* b0       = (const float*)d_in[4];
    const float* Wh       = (const float*)d_in[5];
    const float* bh       = (const float*)d_in[6];
    const float* Wl       = (const float*)d_in[7];
    const float* bl       = (const float*)d_in[8];
    float* out = (float*)d_out;

    const int N = NN, E = EE;

    char* ws = (char*)d_ws;
    size_t off = 0;
    auto alloc = [&](size_t bytes) -> void* {
        void* p = ws + off;
        off += (bytes + 511) & ~(size_t)511;
        return p;
    };
    float* dinv   = (float*)alloc((size_t)N * 4);
    int*   rowptr = (int*)alloc((size_t)(N + 1) * 4);
    int*   fill   = (int*)alloc((size_t)N * 4);
    int*   colsrc = (int*)alloc((size_t)E * 4);
    float* B1     = (float*)alloc((size_t)N * FF * 4);
    float* B2     = (float*)alloc((size_t)N * FF * 4);
    float* XA     = (float*)alloc((size_t)N * FF * 4);
    float* XB     = (float*)alloc((size_t)N * FF * 4);

    // CSR build
    hipMemsetAsync(fill, 0, (size_t)N * 4, stream);
    hist_kernel<<<(E + 255) / 256, 256, 0, stream>>>(dst, fill, E);
    scan_kernel<<<1, 1024, 0, stream>>>(fill, rowptr, N);
    dinv_kernel<<<(N + 255) / 256, 256, 0, stream>>>(rowptr, dinv, N);
    hipMemsetAsync(fill, 0, (size_t)N * 4, stream);
    scatter_kernel<<<(E + 255) / 256, 256, 0, stream>>>(src, dst, rowptr, fill, colsrc, E);

    const float* cur = features;
    float* nxt = XA;
    int spmm_grid = (N + 7) / 8;
    int gemm_grid = (N + 127) / 128;

    for (int layer = 0; layer < 7; ++layer) {
        const float* W; const float* b;
        bool last = (layer == 6);
        if (layer == 0)      { W = W0; b = b0; }
        else if (layer < 6)  { W = Wh + (size_t)(layer - 1) * 384 * 128; b = bh + (layer - 1) * 128; }
        else                 { W = Wl; b = bl; }

        spmm_kernel<<<spmm_grid, 256, 0, stream>>>(B1, cur, cur, dinv, rowptr, colsrc, -1.f, 0.f, N);
        spmm_kernel<<<spmm_grid, 256, 0, stream>>>(B2, B1, cur, dinv, rowptr, colsrc, -2.f, -1.f, N);

        float* dstbuf = last ? out : nxt;
        if (!last)
            gemm_mfma_kernel<128, 8><<<gemm_grid, 256, 0, stream>>>(dstbuf, cur, B1, B2, W, b, N);
        else
            gemm_mfma_kernel<40, 3><<<gemm_grid, 256, 0, stream>>>(dstbuf, cur, B1, B2, W, b, N);

        if (layer < 6) {
            const float* newcur = nxt;
            nxt = (nxt == XA) ? XB : XA;
            cur = newcur;
        }
    }
}

// Round 4
// 2844.381 us; speedup vs baseline: 1.1965x; 1.0914x over previous
//
#include <hip/hip_runtime.h>
#include <hip/hip_bf16.h>

// ChebNet: N=100000, E=1600000, IN=HID=128, OUT=40, K=3, 5 hidden layers.
//  - CSR by dst built per-launch (3-phase multi-block scan).
//  - Per layer: B1 = -spmm(X); B2 = -2*spmm(B1) - X; H = relu([X|B1|B2] @ W + b)
//  - GEMM uses bf16x3 split (hi/lo) MFMA: A*B ~= Ah*Bh + Ah*Bl + Al*Bh, fp32 acc.

#define NN 100000
#define EE 1600000
#define FF 128

typedef __attribute__((ext_vector_type(8))) short short8_t;
typedef __attribute__((ext_vector_type(4))) short short4_t;
typedef __attribute__((ext_vector_type(4))) float floatx4;

// ---------------- CSR build ----------------

__global__ void hist_kernel(const int* __restrict__ dst, int* __restrict__ cnt, int e) {
    int i = blockIdx.x * blockDim.x + threadIdx.x;
    if (i < e) atomicAdd(&cnt[dst[i]], 1);
}

// phase 1: per-block sums of 256 counts
__global__ __launch_bounds__(256) void scan_p1_kernel(const int* __restrict__ cnt,
                                                      int* __restrict__ bsum, int n) {
    __shared__ int red[8];
    int i = blockIdx.x * 256 + threadIdx.x;
    int v = (i < n) ? cnt[i] : 0;
    // wave64 reduce
    for (int off = 32; off > 0; off >>= 1) v += __shfl_down(v, off, 64);
    int wv = threadIdx.x >> 6;
    if ((threadIdx.x & 63) == 0) red[wv] = v;
    __syncthreads();
    if (threadIdx.x == 0) bsum[blockIdx.x] = red[0] + red[1] + red[2] + red[3];
}

// phase 2: exclusive scan of nb block sums (single block, nb <= 1024)
__global__ __launch_bounds__(1024) void scan_p2_kernel(int* __restrict__ bsum, int nb) {
    __shared__ int s[1024];
    int tid = threadIdx.x;
    int v = (tid < nb) ? bsum[tid] : 0;
    s[tid] = v;
    __syncthreads();
    for (int off = 1; off < 1024; off <<= 1) {
        int u = (tid >= off) ? s[tid - off] : 0;
        __syncthreads();
        s[tid] += u;
        __syncthreads();
    }
    if (tid < nb) bsum[tid] = s[tid] - v;   // exclusive
}

// phase 3: block-local exclusive scan + offset -> row_ptr
__global__ __launch_bounds__(256) void scan_p3_kernel(const int* __restrict__ cnt,
                                                      const int* __restrict__ bsum,
                                                      int* __restrict__ row_ptr, int n) {
    __shared__ int s[256];
    int tid = threadIdx.x;
    int i = blockIdx.x * 256 + tid;
    int v = (i < n) ? cnt[i] : 0;
    s[tid] = v;
    __syncthreads();
    for (int off = 1; off < 256; off <<= 1) {
        int u = (tid >= off) ? s[tid - off] : 0;
        __syncthreads();
        s[tid] += u;
        __syncthreads();
    }
    if (i < n) {
        int excl = bsum[blockIdx.x] + s[tid] - v;
        row_ptr[i] = excl;
        if (i == n - 1) row_ptr[n] = excl + v;
    }
}

__global__ void dinv_kernel(const int* __restrict__ row_ptr, float* __restrict__ dinv, int n) {
    int i = blockIdx.x * blockDim.x + threadIdx.x;
    if (i >= n) return;
    int d = row_ptr[i + 1] - row_ptr[i];
    if (d < 1) d = 1;
    dinv[i] = 1.0f / sqrtf((float)d);
}

__global__ void scatter_kernel(const int* __restrict__ src, const int* __restrict__ dst,
                               const int* __restrict__ row_ptr, int* __restrict__ fill,
                               int* __restrict__ col_src, int e) {
    int i = blockIdx.x * blockDim.x + threadIdx.x;
    if (i >= e) return;
    int d = dst[i];
    int pos = row_ptr[d] + atomicAdd(&fill[d], 1);
    col_src[pos] = src[i];
}

// ---------------- SpMM ----------------
// out[d] = alpha*dinv[d]*sum_e dinv[src]*Xin[src] + beta*Xo[d]
// 32 lanes per node, lane = one float4 of the row. 4x unrolled gather pipeline.

__global__ __launch_bounds__(256) void spmm_kernel(
    float* __restrict__ out, const float* __restrict__ Xin, const float* __restrict__ Xo,
    const float* __restrict__ dinv, const int* __restrict__ rp, const int* __restrict__ cs,
    float alpha, float beta, int n)
{
    int slot = threadIdx.x >> 5;
    int lane = threadIdx.x & 31;
    int node = blockIdx.x * 8 + slot;
    if (node >= n) return;
    const float4* X4 = (const float4*)Xin;
    float4 acc = make_float4(0.f, 0.f, 0.f, 0.f);
    int s = rp[node], e = rp[node + 1];
    int i = s;
    for (; i + 4 <= e; i += 4) {
        int s0 = cs[i], s1 = cs[i + 1], s2 = cs[i + 2], s3 = cs[i + 3];
        float w0 = dinv[s0], w1 = dinv[s1], w2 = dinv[s2], w3 = dinv[s3];
        float4 x0 = X4[s0 * 32 + lane];
        float4 x1 = X4[s1 * 32 + lane];
        float4 x2 = X4[s2 * 32 + lane];
        float4 x3 = X4[s3 * 32 + lane];
        acc.x += w0 * x0.x + w1 * x1.x + w2 * x2.x + w3 * x3.x;
        acc.y += w0 * x0.y + w1 * x1.y + w2 * x2.y + w3 * x3.y;
        acc.z += w0 * x0.z + w1 * x1.z + w2 * x2.z + w3 * x3.z;
        acc.w += w0 * x0.w + w1 * x1.w + w2 * x2.w + w3 * x3.w;
    }
    for (; i < e; ++i) {
        int sc_ = cs[i];
        float w = dinv[sc_];
        float4 x = X4[sc_ * 32 + lane];
        acc.x += w * x.x; acc.y += w * x.y; acc.z += w * x.z; acc.w += w * x.w;
    }
    float sc = alpha * dinv[node];
    float4 r;
    if (beta != 0.f) {
        float4 o = ((const float4*)Xo)[node * 32 + lane];
        r.x = sc * acc.x + beta * o.x;
        r.y = sc * acc.y + beta * o.y;
        r.z = sc * acc.z + beta * o.z;
        r.w = sc * acc.w + beta * o.w;
    } else {
        r.x = sc * acc.x; r.y = sc * acc.y; r.z = sc * acc.z; r.w = sc * acc.w;
    }
    ((float4*)out)[node * 32 + lane] = r;
}

// ---------------- bf16x3 MFMA GEMM: H = relu([X0|X1|X2] @ W + b) ----------------

__device__ inline void f2bf_hilo(float x, short* hi, short* lo) {
    union { float f; unsigned u; } a; a.f = x;
    unsigned uh = a.u + 0x7FFFu + ((a.u >> 16) & 1u);
    unsigned short h = (unsigned short)(uh >> 16);
    union { unsigned u; float f; } hf; hf.u = ((unsigned)h) << 16;
    float r = x - hf.f;
    union { float f; unsigned u; } b; b.f = r;
    unsigned ul = b.u + 0x7FFFu + ((b.u >> 16) & 1u);
    *hi = (short)h; *lo = (short)(ul >> 16);
}

typedef __attribute__((ext_vector_type(4))) float accfrag;

template <int OUTC, int NT>
__global__ __launch_bounds__(256) void gemm_mfma_kernel(
    float* __restrict__ out, const float* __restrict__ X0, const float* __restrict__ X1,
    const float* __restrict__ X2, const float* __restrict__ W, const float* __restrict__ bias,
    int n)
{
    __shared__ short Ahi[128 * 40];
    __shared__ short Alo[128 * 40];
    __shared__ short Whi[NT * 16 * 40];
    __shared__ short Wlo[NT * 16 * 40];

    int tid = threadIdx.x;
    int row0 = blockIdx.x * 128;
    int lane = tid & 63;
    int wave = tid >> 6;
    int m15 = lane & 15;
    int quad = lane >> 4;

    accfrag acc[2][NT];
#pragma unroll
    for (int mi = 0; mi < 2; ++mi)
#pragma unroll
        for (int nj = 0; nj < NT; ++nj) acc[mi][nj] = (accfrag){0.f, 0.f, 0.f, 0.f};

    if (OUTC != NT * 16) {
        for (int i = tid; i < (NT * 16 - OUTC) * 40; i += 256) {
            Whi[OUTC * 40 + i] = 0;
            Wlo[OUTC * 40 + i] = 0;
        }
    }

    for (int ks = 0; ks < 12; ++ks) {
        const float* Xp = (ks < 4) ? X0 : (ks < 8) ? X1 : X2;
        int k0in = (ks & 3) * 32;
        int k0g = ks * 32;

#pragma unroll
        for (int i = 0; i < 4; ++i) {
            int q = i * 256 + tid;
            int r = q >> 3;
            int kq = (q & 7) * 4;
            int gr = row0 + r;
            floatx4 v = {0.f, 0.f, 0.f, 0.f};
            if (gr < n) v = *(const floatx4*)&Xp[(size_t)gr * 128 + k0in + kq];
            short h[4], l[4];
            f2bf_hilo(v.x, &h[0], &l[0]);
            f2bf_hilo(v.y, &h[1], &l[1]);
            f2bf_hilo(v.z, &h[2], &l[2]);
            f2bf_hilo(v.w, &h[3], &l[3]);
            short4_t hv = { h[0], h[1], h[2], h[3] };
            short4_t lv = { l[0], l[1], l[2], l[3] };
            *(short4_t*)&Ahi[r * 40 + kq] = hv;
            *(short4_t*)&Alo[r * 40 + kq] = lv;
        }

        if (OUTC == 128) {
#pragma unroll
            for (int i = 0; i < 4; ++i) {
                int q = i * 256 + tid;
                int kr = q >> 5;
                int c4 = (q & 31) * 4;
                floatx4 v = *(const floatx4*)&W[(size_t)(k0g + kr) * 128 + c4];
                short h[4], l[4];
                f2bf_hilo(v.x, &h[0], &l[0]);
                f2bf_hilo(v.y, &h[1], &l[1]);
                f2bf_hilo(v.z, &h[2], &l[2]);
                f2bf_hilo(v.w, &h[3], &l[3]);
#pragma unroll
                for (int j = 0; j < 4; ++j) {
                    Whi[(c4 + j) * 40 + kr] = h[j];
                    Wlo[(c4 + j) * 40 + kr] = l[j];
                }
            }
        } else {
#pragma unroll
            for (int i = 0; i < 2; ++i) {
                int q = i * 256 + tid;
                if (q < 320) {
                    int kr = q / 10;
                    int c4 = (q % 10) * 4;
                    floatx4 v = *(const floatx4*)&W[(size_t)(k0g + kr) * 40 + c4];
                    short h[4], l[4];
                    f2bf_hilo(v.x, &h[0], &l[0]);
                    f2bf_hilo(v.y, &h[1], &l[1]);
                    f2bf_hilo(v.z, &h[2], &l[2]);
                    f2bf_hilo(v.w, &h[3], &l[3]);
#pragma unroll
                    for (int j = 0; j < 4; ++j) {
                        Whi[(c4 + j) * 40 + kr] = h[j];
                        Wlo[(c4 + j) * 40 + kr] = l[j];
                    }
                }
            }
        }
        __syncthreads();

        int mbase = wave * 32;
        short8_t a_hi[2], a_lo[2];
#pragma unroll
        for (int mi = 0; mi < 2; ++mi) {
            int off = (mbase + mi * 16 + m15) * 40 + quad * 8;
            a_hi[mi] = *(const short8_t*)&Ahi[off];
            a_lo[mi] = *(const short8_t*)&Alo[off];
        }
#pragma unroll
        for (int nj = 0; nj < NT; ++nj) {
            int off = (nj * 16 + m15) * 40 + quad * 8;
            short8_t b_hi = *(const short8_t*)&Whi[off];
            short8_t b_lo = *(const short8_t*)&Wlo[off];
#pragma unroll
            for (int mi = 0; mi < 2; ++mi) {
                acc[mi][nj] = __builtin_amdgcn_mfma_f32_16x16x32_bf16(a_hi[mi], b_hi, acc[mi][nj], 0, 0, 0);
                acc[mi][nj] = __builtin_amdgcn_mfma_f32_16x16x32_bf16(a_lo[mi], b_hi, acc[mi][nj], 0, 0, 0);
                acc[mi][nj] = __builtin_amdgcn_mfma_f32_16x16x32_bf16(a_hi[mi], b_lo, acc[mi][nj], 0, 0, 0);
            }
        }
        __syncthreads();
    }

#pragma unroll
    for (int nj = 0; nj < NT; ++nj) {
        int col = nj * 16 + m15;
        float bv = (col < OUTC) ? bias[col] : 0.f;
#pragma unroll
        for (int mi = 0; mi < 2; ++mi) {
#pragma unroll
            for (int reg = 0; reg < 4; ++reg) {
                int gr = row0 + wave * 32 + mi * 16 + quad * 4 + reg;
                if (gr < n && col < OUTC) {
                    float v = acc[mi][nj][reg] + bv;
                    out[(size_t)gr * OUTC + col] = v > 0.f ? v : 0.f;
                }
            }
        }
    }
}

// ---------------- launch ----------------

extern "C" void kernel_launch(void* const* d_in, const int* in_sizes, int n_in,
                              void* d_out, int out_size, void* d_ws, size_t ws_size,
                              hipStream_t stream) {
    const float* features = (const float*)d_in[0];
    const int*   src      = (const int*)d_in[1];
    const int*   dst      = (const int*)d_in[2];
    const float* W0       = (const float*)d_in[3];
    const float* b0       = (const float*)d_in[4];
    const float* Wh       = (const float*)d_in[5];
    const float* bh       = (const float*)d_in[6];
    const float* Wl       = (const float*)d_in[7];
    const float* bl       = (const float*)d_in[8];
    float* out = (float*)d_out;

    const int N = NN, E = EE;
    const int NB = (N + 255) / 256;   // 391 scan blocks

    char* ws = (char*)d_ws;
    size_t off = 0;
    auto alloc = [&](size_t bytes) -> void* {
        void* p = ws + off;
        off += (bytes + 511) & ~(size_t)511;
        return p;
    };
    float* dinv   = (float*)alloc((size_t)N * 4);
    int*   rowptr = (int*)alloc((size_t)(N + 1) * 4);
    int*   fill   = (int*)alloc((size_t)N * 4);
    int*   bsum   = (int*)alloc((size_t)NB * 4);
    int*   colsrc = (int*)alloc((size_t)E * 4);
    float* B1     = (float*)alloc((size_t)N * FF * 4);
    float* B2     = (float*)alloc((size_t)N * FF * 4);
    float* XA     = (float*)alloc((size_t)N * FF * 4);
    float* XB     = (float*)alloc((size_t)N * FF * 4);

    // CSR build
    hipMemsetAsync(fill, 0, (size_t)N * 4, stream);
    hist_kernel<<<(E + 255) / 256, 256, 0, stream>>>(dst, fill, E);
    scan_p1_kernel<<<NB, 256, 0, stream>>>(fill, bsum, N);
    scan_p2_kernel<<<1, 1024, 0, stream>>>(bsum, NB);
    scan_p3_kernel<<<NB, 256, 0, stream>>>(fill, bsum, rowptr, N);
    dinv_kernel<<<(N + 255) / 256, 256, 0, stream>>>(rowptr, dinv, N);
    hipMemsetAsync(fill, 0, (size_t)N * 4, stream);
    scatter_kernel<<<(E + 255) / 256, 256, 0, stream>>>(src, dst, rowptr, fill, colsrc, E);

    const float* cur = features;
    float* nxt = XA;
    int spmm_grid = (N + 7) / 8;
    int gemm_grid = (N + 127) / 128;

    for (int layer = 0; layer < 7; ++layer) {
        const float* W; const float* b;
        bool last = (layer == 6);
        if (layer == 0)      { W = W0; b = b0; }
        else if (layer < 6)  { W = Wh + (size_t)(layer - 1) * 384 * 128; b = bh + (layer - 1) * 128; }
        else                 { W = Wl; b = bl; }

        spmm_kernel<<<spmm_grid, 256, 0, stream>>>(B1, cur, cur, dinv, rowptr, colsrc, -1.f, 0.f, N);
        spmm_kernel<<<spmm_grid, 256, 0, stream>>>(B2, B1, cur, dinv, rowptr, colsrc, -2.f, -1.f, N);

        float* dstbuf = last ? out : nxt;
        if (!last)
            gemm_mfma_kernel<128, 8><<<gemm_grid, 256, 0, stream>>>(dstbuf, cur, B1, B2, W, b, N);
        else
            gemm_mfma_kernel<40, 3><<<gemm_grid, 256, 0, stream>>>(dstbuf, cur, B1, B2, W, b, N);

        if (layer < 6) {
            const float* newcur = nxt;
            nxt = (nxt == XA) ? XB : XA;
            cur = newcur;
        }
    }
}